// Round 1
// baseline (1028.545 us; speedup 1.0000x reference)
//
#include <hip/hip_runtime.h>

#define N_NODES 100000
#define DIM 128
#define N_EDGES 1600000

// ---------------------------------------------------------------------------
// Detect whether edge_index is stored as int64 (odd dwords of non-negative
// int64 values < 2^31 are all zero) or int32. Writes flag[0] = 1 if int64.
// ---------------------------------------------------------------------------
__global__ void detect_kernel(const void* __restrict__ ei, int* __restrict__ flag) {
    __shared__ int any;
    if (threadIdx.x == 0) any = 0;
    __syncthreads();
    const int* p = (const int*)ei;
    int nz = 0;
    for (int i = threadIdx.x; i < 2048; i += 256) nz |= (p[2 * i + 1] != 0);
    if (nz) any = 1;
    __syncthreads();
    if (threadIdx.x == 0) flag[0] = any ? 0 : 1;
}

__device__ __forceinline__ int load_idx(const void* ei, long long pos, int is64) {
    return is64 ? (int)((const long long*)ei)[pos] : ((const int*)ei)[pos];
}

// ---------------------------------------------------------------------------
// Histogram of destination degrees.
// ---------------------------------------------------------------------------
__global__ void hist_kernel(const void* __restrict__ ei, int* __restrict__ deg,
                            const int* __restrict__ flag, int E) {
    int e = blockIdx.x * blockDim.x + threadIdx.x;
    if (e >= E) return;
    int is64 = flag[0];
    int d = load_idx(ei, (long long)E + e, is64);
    atomicAdd(&deg[d], 1);
}

// ---------------------------------------------------------------------------
// Single-block exclusive scan over N (chunked, 1024 threads).
// Writes offsets[0..N] and a working copy in cursor[0..N-1].
// ---------------------------------------------------------------------------
__global__ void scan_kernel(const int* __restrict__ deg, int* __restrict__ offsets,
                            int* __restrict__ cursor, int n) {
    __shared__ int wsum[16];
    __shared__ int chunk_total;
    int t = threadIdx.x;
    int lane = t & 63;
    int wid = t >> 6;
    int carry = 0;
    for (int base = 0; base < n; base += 1024) {
        int i = base + t;
        int v = (i < n) ? deg[i] : 0;
        int x = v;
#pragma unroll
        for (int off = 1; off < 64; off <<= 1) {
            int y = __shfl_up(x, off, 64);
            if (lane >= off) x += y;
        }
        if (lane == 63) wsum[wid] = x;
        __syncthreads();
        if (wid == 0) {
            int s = (lane < 16) ? wsum[lane] : 0;
#pragma unroll
            for (int off = 1; off < 16; off <<= 1) {
                int y = __shfl_up(s, off, 64);
                if (lane >= off) s += y;
            }
            if (lane < 16) wsum[lane] = s;
            if (lane == 15) chunk_total = s;
        }
        __syncthreads();
        int prev = (wid > 0) ? wsum[wid - 1] : 0;
        int excl = carry + prev + (x - v);
        if (i < n) { offsets[i] = excl; cursor[i] = excl; }
        carry += chunk_total;
        __syncthreads();
    }
    if (t == 0) offsets[n] = carry;
}

// ---------------------------------------------------------------------------
// Fill CSR: csr_src[pos] = src for each edge, bucketed by dst.
// ---------------------------------------------------------------------------
__global__ void fill_kernel(const void* __restrict__ ei, int* __restrict__ cursor,
                            int* __restrict__ csr_src, const int* __restrict__ flag,
                            int E) {
    int e = blockIdx.x * blockDim.x + threadIdx.x;
    if (e >= E) return;
    int is64 = flag[0];
    int s = load_idx(ei, e, is64);
    int d = load_idx(ei, (long long)E + e, is64);
    int pos = atomicAdd(&cursor[d], 1);
    csr_src[pos] = s;
}

// ---------------------------------------------------------------------------
// Atomic-free aggregation: agg[n][d] = sum over edges into n of h[src][d].
// 2 nodes per 256-thread block; 128 lanes own feature dim d.
// ---------------------------------------------------------------------------
__global__ void aggregate_kernel(const float* __restrict__ h,
                                 const int* __restrict__ offsets,
                                 const int* __restrict__ csr_src,
                                 float* __restrict__ agg, int n) {
    int node = blockIdx.x * 2 + (threadIdx.x >> 7);
    int d = threadIdx.x & 127;
    if (node >= n) return;
    int beg = offsets[node];
    int end = offsets[node + 1];
    float s0 = 0.f, s1 = 0.f;
    int e = beg;
    for (; e + 2 <= end; e += 2) {
        int a = csr_src[e];
        int b = csr_src[e + 1];
        s0 += h[(size_t)a * DIM + d];
        s1 += h[(size_t)b * DIM + d];
    }
    if (e < end) s0 += h[(size_t)csr_src[e] * DIM + d];
    agg[(size_t)node * DIM + d] = s0 + s1;
}

// ---------------------------------------------------------------------------
// Fused GEMM: out = A @ Wr^T + H @ Wt^T + bias  (+ optional ReLU)
// A,H: [n,128], Wr,Wt: [128,128] row-major [out_col][in_k].
// 128-row tile per block, 8x8 microtile per thread with stride-16 mapping.
// Safe for H == out (each block reads only its own rows before writing them).
// ---------------------------------------------------------------------------
__global__ __launch_bounds__(256, 4)
void gemm_kernel(const float* __restrict__ A,
                 const float* H,
                 const float* __restrict__ Wr,
                 const float* __restrict__ Wt,
                 const float* __restrict__ bias,
                 float* out,
                 int n, int relu) {
    const int KC = 32;
    __shared__ float sIn[128][33];
    __shared__ float sW[128][33];
    int t = threadIdx.x;
    int tr = t & 15;   // row lane group
    int tc = t >> 4;   // col group
    int row0 = blockIdx.x * 128;

    float acc[8][8];
#pragma unroll
    for (int i = 0; i < 8; i++)
#pragma unroll
        for (int j = 0; j < 8; j++) acc[i][j] = 0.f;

    for (int phase = 0; phase < 2; ++phase) {
        const float* In = phase ? H : A;
        const float* W = phase ? Wt : Wr;
        for (int kc = 0; kc < DIM; kc += KC) {
            __syncthreads();
#pragma unroll
            for (int q = 0; q < 4; ++q) {
                int idx = t + q * 256;        // 0..1023
                int r = idx >> 3;             // 0..127
                int k4 = (idx & 7) << 2;      // 0,4,...,28
                int gr = row0 + r;
                if (gr >= n) gr = n - 1;
                float4 v = *(const float4*)(In + (size_t)gr * DIM + kc + k4);
                sIn[r][k4 + 0] = v.x;
                sIn[r][k4 + 1] = v.y;
                sIn[r][k4 + 2] = v.z;
                sIn[r][k4 + 3] = v.w;
                float4 wv = *(const float4*)(W + r * DIM + kc + k4);
                sW[r][k4 + 0] = wv.x;
                sW[r][k4 + 1] = wv.y;
                sW[r][k4 + 2] = wv.z;
                sW[r][k4 + 3] = wv.w;
            }
            __syncthreads();
#pragma unroll 4
            for (int k = 0; k < KC; ++k) {
                float a[8], w[8];
#pragma unroll
                for (int i = 0; i < 8; i++) a[i] = sIn[tr + 16 * i][k];
#pragma unroll
                for (int j = 0; j < 8; j++) w[j] = sW[tc + 16 * j][k];
#pragma unroll
                for (int i = 0; i < 8; i++)
#pragma unroll
                    for (int j = 0; j < 8; j++)
                        acc[i][j] = fmaf(a[i], w[j], acc[i][j]);
            }
        }
    }

#pragma unroll
    for (int i = 0; i < 8; i++) {
        int r = row0 + tr + 16 * i;
        if (r < n) {
#pragma unroll
            for (int j = 0; j < 8; j++) {
                int c = tc + 16 * j;
                float v = acc[i][j] + bias[c];
                if (relu) v = fmaxf(v, 0.f);
                out[(size_t)r * DIM + c] = v;
            }
        }
    }
}

// ---------------------------------------------------------------------------
extern "C" void kernel_launch(void* const* d_in, const int* in_sizes, int n_in,
                              void* d_out, int out_size, void* d_ws, size_t ws_size,
                              hipStream_t stream) {
    const int N = N_NODES, E = N_EDGES;
    const float* x = (const float*)d_in[0];
    const void* ei = d_in[1];
    const float* W1r = (const float*)d_in[2];
    const float* W1t = (const float*)d_in[3];
    const float* b1 = (const float*)d_in[4];
    const float* W2r = (const float*)d_in[5];
    const float* W2t = (const float*)d_in[6];
    const float* b2 = (const float*)d_in[7];
    float* out = (float*)d_out;

    char* w = (char*)d_ws;
    auto alloc = [&](size_t bytes) {
        char* p = w;
        w += (bytes + 255) & ~(size_t)255;
        return p;
    };
    int* flag = (int*)alloc(4);
    int* deg = (int*)alloc((size_t)N * 4);
    int* offsets = (int*)alloc((size_t)(N + 1) * 4);
    int* cursor = (int*)alloc((size_t)N * 4);
    int* csr_src = (int*)alloc((size_t)E * 4);
    float* agg = (float*)alloc((size_t)N * DIM * 4);

    hipMemsetAsync(deg, 0, (size_t)N * 4, stream);
    detect_kernel<<<1, 256, 0, stream>>>(ei, flag);
    hist_kernel<<<(E + 255) / 256, 256, 0, stream>>>(ei, deg, flag, E);
    scan_kernel<<<1, 1024, 0, stream>>>(deg, offsets, cursor, N);
    fill_kernel<<<(E + 255) / 256, 256, 0, stream>>>(ei, cursor, csr_src, flag, E);

    // Layer 1: agg1 = segsum(x), h = relu(agg1@W1r^T + x@W1t^T + b1) -> d_out
    aggregate_kernel<<<N / 2, 256, 0, stream>>>(x, offsets, csr_src, agg, N);
    gemm_kernel<<<(N + 127) / 128, 256, 0, stream>>>(agg, x, W1r, W1t, b1, out, N, 1);

    // Layer 2: agg2 = segsum(h), out = agg2@W2r^T + h@W2t^T + b2 (in-place safe)
    aggregate_kernel<<<N / 2, 256, 0, stream>>>(out, offsets, csr_src, agg, N);
    gemm_kernel<<<(N + 127) / 128, 256, 0, stream>>>(agg, out, W2r, W2t, b2, out, N, 0);
}

// Round 3
// 541.701 us; speedup vs baseline: 1.8987x; 1.8987x over previous
//
#include <hip/hip_runtime.h>

#define NN 100000
#define DIM 128
#define NE 1600000

typedef __attribute__((ext_vector_type(8))) short short8;
typedef __attribute__((ext_vector_type(4))) float f32x4;

// fp32 -> bf16 bits, round-to-nearest-even
__device__ __forceinline__ unsigned f2b(float f) {
    unsigned u = __float_as_uint(f);
    return (u + 0x7FFFu + ((u >> 16) & 1u)) >> 16;
}
__device__ __forceinline__ float blo(unsigned v) { return __uint_as_float(v << 16); }
__device__ __forceinline__ float bhi(unsigned v) { return __uint_as_float(v & 0xFFFF0000u); }

// ---------------------------------------------------------------------------
// int64-vs-int32 edge_index detection (odd dwords all zero => int64)
// ---------------------------------------------------------------------------
__global__ void detect_kernel(const void* __restrict__ ei, int* __restrict__ flag) {
    __shared__ int any;
    if (threadIdx.x == 0) any = 0;
    __syncthreads();
    const int* p = (const int*)ei;
    int nz = 0;
    for (int i = threadIdx.x; i < 2048; i += 256) nz |= (p[2 * i + 1] != 0);
    if (nz) any = 1;
    __syncthreads();
    if (threadIdx.x == 0) flag[0] = any ? 0 : 1;
}

__device__ __forceinline__ int load_idx(const void* ei, long long pos, int is64) {
    return is64 ? (int)((const long long*)ei)[pos] : ((const int*)ei)[pos];
}

// ---------------------------------------------------------------------------
// fp32 -> bf16 bulk conversion (8 elements / thread)
// ---------------------------------------------------------------------------
__global__ void cvt_kernel(const float* __restrict__ in, unsigned short* __restrict__ out, int n8) {
    int i = blockIdx.x * 256 + threadIdx.x;
    if (i >= n8) return;
    const float4* p = (const float4*)in + (size_t)i * 2;
    float4 a = p[0], b = p[1];
    uint4 o;
    o.x = f2b(a.x) | (f2b(a.y) << 16);
    o.y = f2b(a.z) | (f2b(a.w) << 16);
    o.z = f2b(b.x) | (f2b(b.y) << 16);
    o.w = f2b(b.z) | (f2b(b.w) << 16);
    ((uint4*)out)[i] = o;
}

// ---------------------------------------------------------------------------
// CSR build: histogram, 2-level scan, fill
// ---------------------------------------------------------------------------
__global__ void hist_kernel(const void* __restrict__ ei, int* __restrict__ deg,
                            const int* __restrict__ flag, int E) {
    int e = blockIdx.x * blockDim.x + threadIdx.x;
    if (e >= E) return;
    int is64 = flag[0];
    int d = load_idx(ei, (long long)E + e, is64);
    atomicAdd(&deg[d], 1);
}

__global__ void scan1(const int* __restrict__ deg, int* __restrict__ offsets,
                      int* __restrict__ bsum, int n) {
    __shared__ int wsum[4];
    int t = threadIdx.x, lane = t & 63, w = t >> 6;
    int base = blockIdx.x * 1024 + t * 4;
    int a0 = base + 0 < n ? deg[base + 0] : 0;
    int a1 = base + 1 < n ? deg[base + 1] : 0;
    int a2 = base + 2 < n ? deg[base + 2] : 0;
    int a3 = base + 3 < n ? deg[base + 3] : 0;
    int s = a0 + a1 + a2 + a3;
    int x = s;
#pragma unroll
    for (int off = 1; off < 64; off <<= 1) {
        int y = __shfl_up(x, off, 64);
        if (lane >= off) x += y;
    }
    if (lane == 63) wsum[w] = x;
    __syncthreads();
    if (t == 0) {
        int c = 0;
#pragma unroll
        for (int k = 0; k < 4; k++) { int tmp = wsum[k]; wsum[k] = c; c += tmp; }
        bsum[blockIdx.x] = c;
    }
    __syncthreads();
    int excl = wsum[w] + (x - s);
    if (base + 0 < n) offsets[base + 0] = excl;
    if (base + 1 < n) offsets[base + 1] = excl + a0;
    if (base + 2 < n) offsets[base + 2] = excl + a0 + a1;
    if (base + 3 < n) offsets[base + 3] = excl + a0 + a1 + a2;
}

__global__ void scan2(int* __restrict__ bsum, int* __restrict__ offsets, int nb, int n) {
    __shared__ int w0tot;
    int t = threadIdx.x, lane = t & 63, w = t >> 6;
    int v = t < nb ? bsum[t] : 0;
    int x = v;
#pragma unroll
    for (int off = 1; off < 64; off <<= 1) {
        int y = __shfl_up(x, off, 64);
        if (lane >= off) x += y;
    }
    if (t == 63) w0tot = x;
    __syncthreads();
    int excl = x - v + (w ? w0tot : 0);
    if (t < nb) bsum[t] = excl;
    if (t == nb - 1) offsets[n] = excl + v;
}

__global__ void scan3(int* __restrict__ offsets, int* __restrict__ cursor,
                      const int* __restrict__ bsum, int n) {
    int base = blockIdx.x * 1024 + threadIdx.x * 4;
    int add = bsum[blockIdx.x];
#pragma unroll
    for (int j = 0; j < 4; j++) {
        int i = base + j;
        if (i < n) { int v = offsets[i] + add; offsets[i] = v; cursor[i] = v; }
    }
}

__global__ void fill_kernel(const void* __restrict__ ei, int* __restrict__ cursor,
                            int* __restrict__ csr_src, const int* __restrict__ flag, int E) {
    int e = blockIdx.x * blockDim.x + threadIdx.x;
    if (e >= E) return;
    int is64 = flag[0];
    int s = load_idx(ei, e, is64);
    int d = load_idx(ei, (long long)E + e, is64);
    int pos = atomicAdd(&cursor[d], 1);
    csr_src[pos] = s;
}

// ---------------------------------------------------------------------------
// bf16 aggregation: 1 wave per node, lane owns 2 dims (one packed uint).
// fp32 accumulate, bf16 output.
// ---------------------------------------------------------------------------
__global__ void agg_kernel(const unsigned* __restrict__ hb,
                           const int* __restrict__ offsets,
                           const int* __restrict__ csr,
                           unsigned* __restrict__ aggb, int n) {
    int node = blockIdx.x * 4 + (threadIdx.x >> 6);
    int lane = threadIdx.x & 63;
    if (node >= n) return;
    int e = offsets[node], end = offsets[node + 1];
    float s0 = 0.f, s1 = 0.f, t0 = 0.f, t1 = 0.f;
    for (; e + 2 <= end; e += 2) {
        int a = csr[e], b = csr[e + 1];
        unsigned va = hb[a * 64 + lane];
        unsigned vb = hb[b * 64 + lane];
        s0 += blo(va); s1 += bhi(va);
        t0 += blo(vb); t1 += bhi(vb);
    }
    if (e < end) {
        unsigned v = hb[csr[e] * 64 + lane];
        s0 += blo(v); s1 += bhi(v);
    }
    s0 += t0; s1 += t1;
    aggb[node * 64 + lane] = f2b(s0) | (f2b(s1) << 16);
}

// ---------------------------------------------------------------------------
// MFMA bf16 GEMM: out = A@Wr^T + H@Wt^T + bias (+relu for bf16 output).
// 128 rows x 128 cols per block, 4 waves, each wave 32x128.
// XOR-swizzled LDS (st_16x32 style) -> ~2-way bank conflicts only.
// OUTF32=0: bf16 out + relu (layer 1, may alias H buffer: block-local rows only).
// OUTF32=1: fp32 out (layer 2).
// ---------------------------------------------------------------------------
template <int OUTF32>
__global__ __launch_bounds__(256, 2)
void mfma_gemm(const unsigned short* __restrict__ A,
               const unsigned short* __restrict__ H,
               const unsigned short* __restrict__ Wr,
               const unsigned short* __restrict__ Wt,
               const float* __restrict__ bias,
               void* __restrict__ outp, int n) {
    __shared__ __align__(16) char sIn[128 * 256];
    __shared__ __align__(16) char sW[128 * 256];
    int t = threadIdx.x;
    int l = t & 63, w = t >> 6;
    int row0 = blockIdx.x * 128;
    int lr = l & 15;
    int lk = (l >> 4) << 3;  // 0,8,16,24

    f32x4 acc[2][8];
#pragma unroll
    for (int i = 0; i < 2; i++)
#pragma unroll
        for (int j = 0; j < 8; j++) acc[i][j] = (f32x4){0.f, 0.f, 0.f, 0.f};

    for (int phase = 0; phase < 2; ++phase) {
        const unsigned short* In = phase ? H : A;
        const unsigned short* W = phase ? Wt : Wr;
        __syncthreads();  // previous phase done reading LDS
#pragma unroll
        for (int q = 0; q < 8; q++) {
            int idx = q * 256 + t;
            int r = idx >> 4, c = idx & 15;  // 128 rows x 16 chunks of 16B
            int gr = row0 + r; if (gr > n - 1) gr = n - 1;
            uint4 v = ((const uint4*)In)[(size_t)gr * 16 + c];
            *(uint4*)(sIn + r * 256 + ((c * 16) ^ ((r & 7) << 4))) = v;
            uint4 wv = ((const uint4*)W)[r * 16 + c];
            *(uint4*)(sW + r * 256 + ((c * 16) ^ ((r & 7) << 4))) = wv;
        }
        __syncthreads();
#pragma unroll
        for (int ks = 0; ks < 4; ++ks) {
            int kb = (ks * 32 + lk) * 2;  // byte offset of k within row
            short8 av[2], bv[8];
#pragma unroll
            for (int mt = 0; mt < 2; mt++) {
                int r = w * 32 + mt * 16 + lr;
                av[mt] = *(const short8*)(sIn + r * 256 + (kb ^ ((r & 7) << 4)));
            }
#pragma unroll
            for (int nt = 0; nt < 8; nt++) {
                int cw = nt * 16 + lr;
                bv[nt] = *(const short8*)(sW + cw * 256 + (kb ^ ((cw & 7) << 4)));
            }
#pragma unroll
            for (int mt = 0; mt < 2; mt++)
#pragma unroll
                for (int nt = 0; nt < 8; nt++)
                    acc[mt][nt] = __builtin_amdgcn_mfma_f32_16x16x32_bf16(
                        av[mt], bv[nt], acc[mt][nt], 0, 0, 0);
        }
    }

    // C/D layout (m89-verified): col = lane&15, row = (lane>>4)*4 + reg
    int rbase = row0 + w * 32 + ((l >> 4) << 2);
#pragma unroll
    for (int mt = 0; mt < 2; mt++) {
#pragma unroll
        for (int nt = 0; nt < 8; nt++) {
            int col = nt * 16 + lr;
            float bc = bias[col];
#pragma unroll
            for (int j = 0; j < 4; j++) {
                int row = rbase + mt * 16 + j;
                if (row < n) {
                    float v = acc[mt][nt][j] + bc;
                    if (OUTF32) {
                        ((float*)outp)[(size_t)row * DIM + col] = v;
                    } else {
                        v = fmaxf(v, 0.f);
                        ((unsigned short*)outp)[(size_t)row * DIM + col] =
                            (unsigned short)f2b(v);
                    }
                }
            }
        }
    }
}

// ---------------------------------------------------------------------------
extern "C" void kernel_launch(void* const* d_in, const int* in_sizes, int n_in,
                              void* d_out, int out_size, void* d_ws, size_t ws_size,
                              hipStream_t stream) {
    const int N = NN, E = NE;
    const float* x = (const float*)d_in[0];
    const void* ei = d_in[1];
    const float* W1r = (const float*)d_in[2];
    const float* W1t = (const float*)d_in[3];
    const float* b1 = (const float*)d_in[4];
    const float* W2r = (const float*)d_in[5];
    const float* W2t = (const float*)d_in[6];
    const float* b2 = (const float*)d_in[7];
    float* out = (float*)d_out;

    char* wsp = (char*)d_ws;
    auto alloc = [&](size_t bytes) {
        char* p = wsp;
        wsp += (bytes + 255) & ~(size_t)255;
        return p;
    };
    int* flag = (int*)alloc(4);
    int* deg = (int*)alloc((size_t)N * 4);
    int* offsets = (int*)alloc((size_t)(N + 1) * 4);
    int* cursor = (int*)alloc((size_t)N * 4);
    int* bsum = (int*)alloc(512);
    int* csr_src = (int*)alloc((size_t)E * 4);
    unsigned short* w1rb = (unsigned short*)alloc(DIM * DIM * 2);
    unsigned short* w1tb = (unsigned short*)alloc(DIM * DIM * 2);
    unsigned short* w2rb = (unsigned short*)alloc(DIM * DIM * 2);
    unsigned short* w2tb = (unsigned short*)alloc(DIM * DIM * 2);
    unsigned short* xb = (unsigned short*)alloc((size_t)N * DIM * 2);   // becomes h (bf16)
    unsigned short* aggb = (unsigned short*)alloc((size_t)N * DIM * 2); // agg1 then agg2

    const int NB = (N + 1023) / 1024;  // 98

    hipMemsetAsync(deg, 0, (size_t)N * 4, stream);
    detect_kernel<<<1, 256, 0, stream>>>(ei, flag);

    // bf16 conversions (independent of CSR build)
    cvt_kernel<<<(N * DIM / 8 + 255) / 256, 256, 0, stream>>>(x, xb, N * DIM / 8);
    cvt_kernel<<<8, 256, 0, stream>>>(W1r, w1rb, DIM * DIM / 8);
    cvt_kernel<<<8, 256, 0, stream>>>(W1t, w1tb, DIM * DIM / 8);
    cvt_kernel<<<8, 256, 0, stream>>>(W2r, w2rb, DIM * DIM / 8);
    cvt_kernel<<<8, 256, 0, stream>>>(W2t, w2tb, DIM * DIM / 8);

    // CSR by destination
    hist_kernel<<<(E + 255) / 256, 256, 0, stream>>>(ei, deg, flag, E);
    scan1<<<NB, 256, 0, stream>>>(deg, offsets, bsum, N);
    scan2<<<1, 128, 0, stream>>>(bsum, offsets, NB, N);
    scan3<<<NB, 256, 0, stream>>>(offsets, cursor, bsum, N);
    fill_kernel<<<(E + 255) / 256, 256, 0, stream>>>(ei, cursor, csr_src, flag, E);

    // Layer 1: agg1 = segsum(xb); h = relu(agg1@W1r^T + x@W1t^T + b1) -> xb (bf16)
    agg_kernel<<<N / 4, 256, 0, stream>>>((const unsigned*)xb, offsets, csr_src,
                                          (unsigned*)aggb, N);
    mfma_gemm<0><<<(N + 127) / 128, 256, 0, stream>>>(aggb, xb, w1rb, w1tb, b1, xb, N);

    // Layer 2: agg2 = segsum(h); out = agg2@W2r^T + h@W2t^T + b2 (fp32)
    agg_kernel<<<N / 4, 256, 0, stream>>>((const unsigned*)xb, offsets, csr_src,
                                          (unsigned*)aggb, N);
    mfma_gemm<1><<<(N + 127) / 128, 256, 0, stream>>>(aggb, xb, w2rb, w2tb, b2, out, N);
}

// Round 4
// 476.483 us; speedup vs baseline: 2.1586x; 1.1369x over previous
//
#include <hip/hip_runtime.h>

#define NN 100000
#define DIM 128
#define NE 1600000

typedef __attribute__((ext_vector_type(8))) short short8;
typedef __attribute__((ext_vector_type(4))) float f32x4;

// fp32 -> bf16 bits, round-to-nearest-even
__device__ __forceinline__ unsigned f2b(float f) {
    unsigned u = __float_as_uint(f);
    return (u + 0x7FFFu + ((u >> 16) & 1u)) >> 16;
}
__device__ __forceinline__ float blo(unsigned v) { return __uint_as_float(v << 16); }
__device__ __forceinline__ float bhi(unsigned v) { return __uint_as_float(v & 0xFFFF0000u); }

// dword index of element `pos` in the (possibly int64) edge array:
// for non-negative int64 < 2^31, the value lives in the low dword.
__device__ __forceinline__ long long didx(long long pos, int is64) {
    return is64 ? 2 * pos : pos;
}

// ---------------------------------------------------------------------------
// int64-vs-int32 edge_index detection (odd dwords all zero => int64)
// ---------------------------------------------------------------------------
__global__ void detect_kernel(const void* __restrict__ ei, int* __restrict__ flag) {
    __shared__ int any;
    if (threadIdx.x == 0) any = 0;
    __syncthreads();
    const int* p = (const int*)ei;
    int nz = 0;
    for (int i = threadIdx.x; i < 2048; i += 256) nz |= (p[2 * i + 1] != 0);
    if (nz) any = 1;
    __syncthreads();
    if (threadIdx.x == 0) flag[0] = any ? 0 : 1;
}

// ---------------------------------------------------------------------------
// fp32 -> bf16 bulk conversion (8 elements / thread)
// ---------------------------------------------------------------------------
__global__ void cvt_kernel(const float* __restrict__ in, unsigned short* __restrict__ out, int n8) {
    int i = blockIdx.x * 256 + threadIdx.x;
    if (i >= n8) return;
    const float4* p = (const float4*)in + (size_t)i * 2;
    float4 a = p[0], b = p[1];
    uint4 o;
    o.x = f2b(a.x) | (f2b(a.y) << 16);
    o.y = f2b(a.z) | (f2b(a.w) << 16);
    o.z = f2b(b.x) | (f2b(b.y) << 16);
    o.w = f2b(b.z) | (f2b(b.w) << 16);
    ((uint4*)out)[i] = o;
}

// ---------------------------------------------------------------------------
// Histogram of destination degrees (dword loads, 4 edges/thread for ILP).
// ---------------------------------------------------------------------------
__global__ void hist_kernel(const void* __restrict__ ei, int* __restrict__ deg,
                            const int* __restrict__ flag, int E) {
    int is64 = flag[0];
    const int* p = (const int*)ei;
    int base = blockIdx.x * 1024 + threadIdx.x;
    int d0 = -1, d1 = -1, d2 = -1, d3 = -1;
    if (base + 0 * 256 < E) d0 = p[didx((long long)E + base + 0 * 256, is64)];
    if (base + 1 * 256 < E) d1 = p[didx((long long)E + base + 1 * 256, is64)];
    if (base + 2 * 256 < E) d2 = p[didx((long long)E + base + 2 * 256, is64)];
    if (base + 3 * 256 < E) d3 = p[didx((long long)E + base + 3 * 256, is64)];
    if (d0 >= 0) atomicAdd(&deg[d0], 1);
    if (d1 >= 0) atomicAdd(&deg[d1], 1);
    if (d2 >= 0) atomicAdd(&deg[d2], 1);
    if (d3 >= 0) atomicAdd(&deg[d3], 1);
}

// ---------------------------------------------------------------------------
// Two-level exclusive scan over N
// ---------------------------------------------------------------------------
__global__ void scan1(const int* __restrict__ deg, int* __restrict__ offsets,
                      int* __restrict__ bsum, int n) {
    __shared__ int wsum[4];
    int t = threadIdx.x, lane = t & 63, w = t >> 6;
    int base = blockIdx.x * 1024 + t * 4;
    int a0 = base + 0 < n ? deg[base + 0] : 0;
    int a1 = base + 1 < n ? deg[base + 1] : 0;
    int a2 = base + 2 < n ? deg[base + 2] : 0;
    int a3 = base + 3 < n ? deg[base + 3] : 0;
    int s = a0 + a1 + a2 + a3;
    int x = s;
#pragma unroll
    for (int off = 1; off < 64; off <<= 1) {
        int y = __shfl_up(x, off, 64);
        if (lane >= off) x += y;
    }
    if (lane == 63) wsum[w] = x;
    __syncthreads();
    if (t == 0) {
        int c = 0;
#pragma unroll
        for (int k = 0; k < 4; k++) { int tmp = wsum[k]; wsum[k] = c; c += tmp; }
        bsum[blockIdx.x] = c;
    }
    __syncthreads();
    int excl = wsum[w] + (x - s);
    if (base + 0 < n) offsets[base + 0] = excl;
    if (base + 1 < n) offsets[base + 1] = excl + a0;
    if (base + 2 < n) offsets[base + 2] = excl + a0 + a1;
    if (base + 3 < n) offsets[base + 3] = excl + a0 + a1 + a2;
}

__global__ void scan2(int* __restrict__ bsum, int* __restrict__ offsets, int nb, int n) {
    __shared__ int w0tot;
    int t = threadIdx.x, lane = t & 63, w = t >> 6;
    int v = t < nb ? bsum[t] : 0;
    int x = v;
#pragma unroll
    for (int off = 1; off < 64; off <<= 1) {
        int y = __shfl_up(x, off, 64);
        if (lane >= off) x += y;
    }
    if (t == 63) w0tot = x;
    __syncthreads();
    int excl = x - v + (w ? w0tot : 0);
    if (t < nb) bsum[t] = excl;
    if (t == nb - 1) offsets[n] = excl + v;
}

__global__ void scan3(int* __restrict__ offsets, int* __restrict__ cursor,
                      const int* __restrict__ bsum, int n) {
    int base = blockIdx.x * 1024 + threadIdx.x * 4;
    int add = bsum[blockIdx.x];
#pragma unroll
    for (int j = 0; j < 4; j++) {
        int i = base + j;
        if (i < n) { int v = offsets[i] + add; offsets[i] = v; cursor[i] = v; }
    }
}

// ---------------------------------------------------------------------------
// CSR fill, XCD-range partitioned: grid = 8 ranges x 64 chunks (512 blocks).
// Block bx: dst range = bx & 7 (rides the round-robin block->XCD mapping so
// each XCD's 800 KB csr frontier stays L2-resident -> full-line writebacks),
// chunk = bx >> 3. Ranges are disjoint => atomics correct regardless of
// the actual XCD mapping; the mapping only affects locality.
// ---------------------------------------------------------------------------
#define FILL_CHUNK (NE / 64)
__global__ __launch_bounds__(256)
void fill_kernel(const void* __restrict__ ei, int* __restrict__ cursor,
                 int* __restrict__ csr_src, const int* __restrict__ flag, int E) {
    const int r = blockIdx.x & 7;
    const int c = blockIdx.x >> 3;
    const int is64 = flag[0];
    const int* p = (const int*)ei;
    const int lo = r * (NN / 8), hi = lo + (NN / 8);
    const int beg = c * FILL_CHUNK;
    const int end = min(beg + FILL_CHUNK, E);
    for (int i = beg + (int)threadIdx.x; i < end; i += 1024) {
        int e1 = i + 256, e2 = i + 512, e3 = i + 768;
        int d0 = p[didx((long long)E + i, is64)];
        int d1 = e1 < end ? p[didx((long long)E + e1, is64)] : -1;
        int d2 = e2 < end ? p[didx((long long)E + e2, is64)] : -1;
        int d3 = e3 < end ? p[didx((long long)E + e3, is64)] : -1;
        if (d0 >= lo && d0 < hi) csr_src[atomicAdd(&cursor[d0], 1)] = p[didx(i, is64)];
        if (d1 >= lo && d1 < hi) csr_src[atomicAdd(&cursor[d1], 1)] = p[didx(e1, is64)];
        if (d2 >= lo && d2 < hi) csr_src[atomicAdd(&cursor[d2], 1)] = p[didx(e2, is64)];
        if (d3 >= lo && d3 < hi) csr_src[atomicAdd(&cursor[d3], 1)] = p[didx(e3, is64)];
    }
}

// ---------------------------------------------------------------------------
// bf16 aggregation: 1 wave per node, lane owns 2 dims (one packed uint).
// 4-edge unroll: 4 independent gathers in flight per lane (MLP).
// ---------------------------------------------------------------------------
__global__ void agg_kernel(const unsigned* __restrict__ hb,
                           const int* __restrict__ offsets,
                           const int* __restrict__ csr,
                           unsigned* __restrict__ aggb, int n) {
    int node = blockIdx.x * 4 + (threadIdx.x >> 6);
    int lane = threadIdx.x & 63;
    if (node >= n) return;
    int e = offsets[node], end = offsets[node + 1];
    float s0 = 0.f, s1 = 0.f, t0 = 0.f, t1 = 0.f;
    float u0 = 0.f, u1 = 0.f, v0 = 0.f, v1 = 0.f;
    for (; e + 4 <= end; e += 4) {
        int a = csr[e], b = csr[e + 1], c = csr[e + 2], d = csr[e + 3];
        unsigned va = hb[a * 64 + lane];
        unsigned vb = hb[b * 64 + lane];
        unsigned vc = hb[c * 64 + lane];
        unsigned vd = hb[d * 64 + lane];
        s0 += blo(va); s1 += bhi(va);
        t0 += blo(vb); t1 += bhi(vb);
        u0 += blo(vc); u1 += bhi(vc);
        v0 += blo(vd); v1 += bhi(vd);
    }
    for (; e < end; ++e) {
        unsigned v = hb[csr[e] * 64 + lane];
        s0 += blo(v); s1 += bhi(v);
    }
    s0 += t0 + u0 + v0;
    s1 += t1 + u1 + v1;
    aggb[node * 64 + lane] = f2b(s0) | (f2b(s1) << 16);
}

// ---------------------------------------------------------------------------
// MFMA bf16 GEMM: out = A@Wr^T + H@Wt^T + bias (+relu for bf16 output).
// 128x128 tile per block, 4 waves; XOR-swizzled LDS.
// ---------------------------------------------------------------------------
template <int OUTF32>
__global__ __launch_bounds__(256, 2)
void mfma_gemm(const unsigned short* __restrict__ A,
               const unsigned short* __restrict__ H,
               const unsigned short* __restrict__ Wr,
               const unsigned short* __restrict__ Wt,
               const float* __restrict__ bias,
               void* __restrict__ outp, int n) {
    __shared__ __align__(16) char sIn[128 * 256];
    __shared__ __align__(16) char sW[128 * 256];
    int t = threadIdx.x;
    int l = t & 63, w = t >> 6;
    int row0 = blockIdx.x * 128;
    int lr = l & 15;
    int lk = (l >> 4) << 3;  // 0,8,16,24

    f32x4 acc[2][8];
#pragma unroll
    for (int i = 0; i < 2; i++)
#pragma unroll
        for (int j = 0; j < 8; j++) acc[i][j] = (f32x4){0.f, 0.f, 0.f, 0.f};

    for (int phase = 0; phase < 2; ++phase) {
        const unsigned short* In = phase ? H : A;
        const unsigned short* W = phase ? Wt : Wr;
        __syncthreads();  // previous phase done reading LDS
#pragma unroll
        for (int q = 0; q < 8; q++) {
            int idx = q * 256 + t;
            int r = idx >> 4, c = idx & 15;  // 128 rows x 16 chunks of 16B
            int gr = row0 + r; if (gr > n - 1) gr = n - 1;
            uint4 v = ((const uint4*)In)[(size_t)gr * 16 + c];
            *(uint4*)(sIn + r * 256 + ((c * 16) ^ ((r & 7) << 4))) = v;
            uint4 wv = ((const uint4*)W)[r * 16 + c];
            *(uint4*)(sW + r * 256 + ((c * 16) ^ ((r & 7) << 4))) = wv;
        }
        __syncthreads();
#pragma unroll
        for (int ks = 0; ks < 4; ++ks) {
            int kb = (ks * 32 + lk) * 2;  // byte offset of k within row
            short8 av[2], bv[8];
#pragma unroll
            for (int mt = 0; mt < 2; mt++) {
                int r = w * 32 + mt * 16 + lr;
                av[mt] = *(const short8*)(sIn + r * 256 + (kb ^ ((r & 7) << 4)));
            }
#pragma unroll
            for (int nt = 0; nt < 8; nt++) {
                int cw = nt * 16 + lr;
                bv[nt] = *(const short8*)(sW + cw * 256 + (kb ^ ((cw & 7) << 4)));
            }
#pragma unroll
            for (int mt = 0; mt < 2; mt++)
#pragma unroll
                for (int nt = 0; nt < 8; nt++)
                    acc[mt][nt] = __builtin_amdgcn_mfma_f32_16x16x32_bf16(
                        av[mt], bv[nt], acc[mt][nt], 0, 0, 0);
        }
    }

    // C/D layout (m89-verified): col = lane&15, row = (lane>>4)*4 + reg
    int rbase = row0 + w * 32 + ((l >> 4) << 2);
#pragma unroll
    for (int mt = 0; mt < 2; mt++) {
#pragma unroll
        for (int nt = 0; nt < 8; nt++) {
            int col = nt * 16 + lr;
            float bc = bias[col];
#pragma unroll
            for (int j = 0; j < 4; j++) {
                int row = rbase + mt * 16 + j;
                if (row < n) {
                    float v = acc[mt][nt][j] + bc;
                    if (OUTF32) {
                        ((float*)outp)[(size_t)row * DIM + col] = v;
                    } else {
                        v = fmaxf(v, 0.f);
                        ((unsigned short*)outp)[(size_t)row * DIM + col] =
                            (unsigned short)f2b(v);
                    }
                }
            }
        }
    }
}

// ---------------------------------------------------------------------------
extern "C" void kernel_launch(void* const* d_in, const int* in_sizes, int n_in,
                              void* d_out, int out_size, void* d_ws, size_t ws_size,
                              hipStream_t stream) {
    const int N = NN, E = NE;
    const float* x = (const float*)d_in[0];
    const void* ei = d_in[1];
    const float* W1r = (const float*)d_in[2];
    const float* W1t = (const float*)d_in[3];
    const float* b1 = (const float*)d_in[4];
    const float* W2r = (const float*)d_in[5];
    const float* W2t = (const float*)d_in[6];
    const float* b2 = (const float*)d_in[7];
    float* out = (float*)d_out;

    char* wsp = (char*)d_ws;
    auto alloc = [&](size_t bytes) {
        char* p = wsp;
        wsp += (bytes + 255) & ~(size_t)255;
        return p;
    };
    int* flag = (int*)alloc(4);
    int* deg = (int*)alloc((size_t)N * 4);
    int* offsets = (int*)alloc((size_t)(N + 1) * 4);
    int* cursor = (int*)alloc((size_t)N * 4);
    int* bsum = (int*)alloc(512);
    int* csr_src = (int*)alloc((size_t)E * 4);
    unsigned short* w1rb = (unsigned short*)alloc(DIM * DIM * 2);
    unsigned short* w1tb = (unsigned short*)alloc(DIM * DIM * 2);
    unsigned short* w2rb = (unsigned short*)alloc(DIM * DIM * 2);
    unsigned short* w2tb = (unsigned short*)alloc(DIM * DIM * 2);
    unsigned short* xb = (unsigned short*)alloc((size_t)N * DIM * 2);   // becomes h (bf16)
    unsigned short* aggb = (unsigned short*)alloc((size_t)N * DIM * 2); // agg1 then agg2

    const int NB = (N + 1023) / 1024;  // 98

    hipMemsetAsync(deg, 0, (size_t)N * 4, stream);
    detect_kernel<<<1, 256, 0, stream>>>(ei, flag);

    // bf16 conversions (independent of CSR build)
    cvt_kernel<<<(N * DIM / 8 + 255) / 256, 256, 0, stream>>>(x, xb, N * DIM / 8);
    cvt_kernel<<<8, 256, 0, stream>>>(W1r, w1rb, DIM * DIM / 8);
    cvt_kernel<<<8, 256, 0, stream>>>(W1t, w1tb, DIM * DIM / 8);
    cvt_kernel<<<8, 256, 0, stream>>>(W2r, w2rb, DIM * DIM / 8);
    cvt_kernel<<<8, 256, 0, stream>>>(W2t, w2tb, DIM * DIM / 8);

    // CSR by destination
    hist_kernel<<<(E + 1023) / 1024, 256, 0, stream>>>(ei, deg, flag, E);
    scan1<<<NB, 256, 0, stream>>>(deg, offsets, bsum, N);
    scan2<<<1, 128, 0, stream>>>(bsum, offsets, NB, N);
    scan3<<<NB, 256, 0, stream>>>(offsets, cursor, bsum, N);
    fill_kernel<<<512, 256, 0, stream>>>(ei, cursor, csr_src, flag, E);

    // Layer 1: agg1 = segsum(xb); h = relu(agg1@W1r^T + x@W1t^T + b1) -> xb (bf16)
    agg_kernel<<<N / 4, 256, 0, stream>>>((const unsigned*)xb, offsets, csr_src,
                                          (unsigned*)aggb, N);
    mfma_gemm<0><<<(N + 127) / 128, 256, 0, stream>>>(aggb, xb, w1rb, w1tb, b1, xb, N);

    // Layer 2: agg2 = segsum(h); out = agg2@W2r^T + h@W2t^T + b2 (fp32)
    agg_kernel<<<N / 4, 256, 0, stream>>>((const unsigned*)xb, offsets, csr_src,
                                          (unsigned*)aggb, N);
    mfma_gemm<1><<<(N + 127) / 128, 256, 0, stream>>>(aggb, xb, w2rb, w2tb, b2, out, N);
}

// Round 7
// 455.042 us; speedup vs baseline: 2.2603x; 1.0471x over previous
//
#include <hip/hip_runtime.h>

#define NN 100000
#define DIM 128
#define NE 1600000
#define NCHUNK 64
#define FILL_CHUNK (NE / NCHUNK)    // 25000

typedef __attribute__((ext_vector_type(8))) short short8;
typedef __attribute__((ext_vector_type(4))) float f32x4;

// fp32 -> bf16 bits, round-to-nearest-even
__device__ __forceinline__ unsigned f2b(float f) {
    unsigned u = __float_as_uint(f);
    return (u + 0x7FFFu + ((u >> 16) & 1u)) >> 16;
}
__device__ __forceinline__ float blo(unsigned v) { return __uint_as_float(v << 16); }
__device__ __forceinline__ float bhi(unsigned v) { return __uint_as_float(v & 0xFFFF0000u); }

// dword index of element `pos` in the (possibly int64) edge array:
// non-negative int64 < 2^31 lives in the low dword.
__device__ __forceinline__ long long didx(long long pos, int is64) {
    return is64 ? 2 * pos : pos;
}

// ---------------------------------------------------------------------------
// int64-vs-int32 edge_index detection (odd dwords all zero => int64)
// ---------------------------------------------------------------------------
__global__ void detect_kernel(const void* __restrict__ ei, int* __restrict__ flag) {
    __shared__ int any;
    if (threadIdx.x == 0) any = 0;
    __syncthreads();
    const int* p = (const int*)ei;
    int nz = 0;
    for (int i = threadIdx.x; i < 2048; i += 256) nz |= (p[2 * i + 1] != 0);
    if (nz) any = 1;
    __syncthreads();
    if (threadIdx.x == 0) flag[0] = any ? 0 : 1;
}

// ---------------------------------------------------------------------------
// fp32 -> bf16 bulk conversion (8 elements / thread)
// ---------------------------------------------------------------------------
__global__ void cvt_kernel(const float* __restrict__ in, unsigned short* __restrict__ out, int n8) {
    int i = blockIdx.x * 256 + threadIdx.x;
    if (i >= n8) return;
    const float4* p = (const float4*)in + (size_t)i * 2;
    float4 a = p[0], b = p[1];
    uint4 o;
    o.x = f2b(a.x) | (f2b(a.y) << 16);
    o.y = f2b(a.z) | (f2b(a.w) << 16);
    o.z = f2b(b.x) | (f2b(b.y) << 16);
    o.w = f2b(b.z) | (f2b(b.w) << 16);
    ((uint4*)out)[i] = o;
}

// all 4 weight matrices in one launch: 4 x 2048 chunks of 8
__global__ void cvtw_kernel(const float* __restrict__ w0, const float* __restrict__ w1,
                            const float* __restrict__ w2, const float* __restrict__ w3,
                            unsigned short* __restrict__ o0, unsigned short* __restrict__ o1,
                            unsigned short* __restrict__ o2, unsigned short* __restrict__ o3) {
    int i = blockIdx.x * 256 + threadIdx.x;      // 0..8191
    int which = i >> 11, j = i & 2047;
    const float* in = which == 0 ? w0 : which == 1 ? w1 : which == 2 ? w2 : w3;
    unsigned short* out = which == 0 ? o0 : which == 1 ? o1 : which == 2 ? o2 : o3;
    const float4* p = (const float4*)in + (size_t)j * 2;
    float4 a = p[0], b = p[1];
    uint4 o;
    o.x = f2b(a.x) | (f2b(a.y) << 16);
    o.y = f2b(a.z) | (f2b(a.w) << 16);
    o.z = f2b(b.x) | (f2b(b.y) << 16);
    o.w = f2b(b.z) | (f2b(b.w) << 16);
    ((uint4*)out)[j] = o;
}

// ---------------------------------------------------------------------------
// Histogram of destination degrees (dword loads, 4 edges/thread for ILP).
// ---------------------------------------------------------------------------
__global__ void hist_kernel(const void* __restrict__ ei, int* __restrict__ deg,
                            const int* __restrict__ flag, int E) {
    int is64 = flag[0];
    const int* p = (const int*)ei;
    int base = blockIdx.x * 1024 + threadIdx.x;
    int d0 = -1, d1 = -1, d2 = -1, d3 = -1;
    if (base + 0 * 256 < E) d0 = p[didx((long long)E + base + 0 * 256, is64)];
    if (base + 1 * 256 < E) d1 = p[didx((long long)E + base + 1 * 256, is64)];
    if (base + 2 * 256 < E) d2 = p[didx((long long)E + base + 2 * 256, is64)];
    if (base + 3 * 256 < E) d3 = p[didx((long long)E + base + 3 * 256, is64)];
    if (d0 >= 0) atomicAdd(&deg[d0], 1);
    if (d1 >= 0) atomicAdd(&deg[d1], 1);
    if (d2 >= 0) atomicAdd(&deg[d2], 1);
    if (d3 >= 0) atomicAdd(&deg[d3], 1);
}

// ---------------------------------------------------------------------------
// Two-level exclusive scan over N
// ---------------------------------------------------------------------------
__global__ void scan1(const int* __restrict__ deg, int* __restrict__ offsets,
                      int* __restrict__ bsum, int n) {
    __shared__ int wsum[4];
    int t = threadIdx.x, lane = t & 63, w = t >> 6;
    int base = blockIdx.x * 1024 + t * 4;
    int a0 = base + 0 < n ? deg[base + 0] : 0;
    int a1 = base + 1 < n ? deg[base + 1] : 0;
    int a2 = base + 2 < n ? deg[base + 2] : 0;
    int a3 = base + 3 < n ? deg[base + 3] : 0;
    int s = a0 + a1 + a2 + a3;
    int x = s;
#pragma unroll
    for (int off = 1; off < 64; off <<= 1) {
        int y = __shfl_up(x, off, 64);
        if (lane >= off) x += y;
    }
    if (lane == 63) wsum[w] = x;
    __syncthreads();
    if (t == 0) {
        int c = 0;
#pragma unroll
        for (int k = 0; k < 4; k++) { int tmp = wsum[k]; wsum[k] = c; c += tmp; }
        bsum[blockIdx.x] = c;
    }
    __syncthreads();
    int excl = wsum[w] + (x - s);
    if (base + 0 < n) offsets[base + 0] = excl;
    if (base + 1 < n) offsets[base + 1] = excl + a0;
    if (base + 2 < n) offsets[base + 2] = excl + a0 + a1;
    if (base + 3 < n) offsets[base + 3] = excl + a0 + a1 + a2;
}

__global__ void scan2(int* __restrict__ bsum, int* __restrict__ offsets, int nb, int n) {
    __shared__ int w0tot;
    int t = threadIdx.x, lane = t & 63, w = t >> 6;
    int v = t < nb ? bsum[t] : 0;
    int x = v;
#pragma unroll
    for (int off = 1; off < 64; off <<= 1) {
        int y = __shfl_up(x, off, 64);
        if (lane >= off) x += y;
    }
    if (t == 63) w0tot = x;
    __syncthreads();
    int excl = x - v + (w ? w0tot : 0);
    if (t < nb) bsum[t] = excl;
    if (t == nb - 1) offsets[n] = excl + v;
}

__global__ void scan3(int* __restrict__ offsets, int* __restrict__ cursor,
                      const int* __restrict__ bsum, int n) {
    int base = blockIdx.x * 1024 + threadIdx.x * 4;
    int add = bsum[blockIdx.x];
#pragma unroll
    for (int j = 0; j < 4; j++) {
        int i = base + j;
        if (i < n) { int v = offsets[i] + add; offsets[i] = v; cursor[i] = v; }
    }
}

// ---------------------------------------------------------------------------
// CSR fill, XCD-aware with bounded exactly-once claiming.
// Grid = NCHUNK chunks x 8 blocks. The 8 blocks sharing chunk c claim the
// 8 dst-ranges of that chunk via at most 8 atomicCAS attempts, trying the
// block's REAL XCD (HW_REG_XCC_ID, m09-verified on gfx950) first.
// Pigeonhole: 8 blocks, 8 slots, each CAS-claims exactly one distinct slot
// => every (range,chunk) item processed exactly once, for ANY block->XCD
// mapping; the mapping only affects locality. No spin loops, no waiting.
// ---------------------------------------------------------------------------
__global__ __launch_bounds__(256)
void fill_kernel(const void* __restrict__ ei, int* __restrict__ cursor,
                 int* __restrict__ csr_src, const int* __restrict__ flag,
                 int* __restrict__ claim, int E) {
    const int c = blockIdx.x >> 3;   // chunk
    const int is64 = flag[0];
    const int* p = (const int*)ei;
    const int t = threadIdx.x;

    int xcd;
    asm volatile("s_getreg_b32 %0, hwreg(HW_REG_XCC_ID)" : "=s"(xcd));
    xcd &= 7;

    __shared__ int s_r;
    if (t == 0) {
        int got = -1;
#pragma unroll
        for (int k = 0; k < 8; k++) {
            int r = (xcd + k) & 7;
            if (atomicCAS(&claim[c * 8 + r], 0, 1) == 0) { got = r; break; }
        }
        s_r = got;   // guaranteed >= 0 by pigeonhole
    }
    __syncthreads();
    const int r = s_r;
    if (r < 0) return;  // unreachable; defensive

    const int lo = r * (NN / 8), hi = lo + (NN / 8);
    const int beg = c * FILL_CHUNK;
    const int end = min(beg + FILL_CHUNK, E);
    for (int i = beg + t; i < end; i += 1024) {
        int e1 = i + 256, e2 = i + 512, e3 = i + 768;
        int d0 = p[didx((long long)E + i, is64)];
        int d1 = e1 < end ? p[didx((long long)E + e1, is64)] : -1;
        int d2 = e2 < end ? p[didx((long long)E + e2, is64)] : -1;
        int d3 = e3 < end ? p[didx((long long)E + e3, is64)] : -1;
        if (d0 >= lo && d0 < hi) csr_src[atomicAdd(&cursor[d0], 1)] = p[didx(i, is64)];
        if (d1 >= lo && d1 < hi) csr_src[atomicAdd(&cursor[d1], 1)] = p[didx(e1, is64)];
        if (d2 >= lo && d2 < hi) csr_src[atomicAdd(&cursor[d2], 1)] = p[didx(e2, is64)];
        if (d3 >= lo && d3 < hi) csr_src[atomicAdd(&cursor[d3], 1)] = p[didx(e3, is64)];
    }
}

// ---------------------------------------------------------------------------
// bf16 aggregation: 1 wave per node, lane owns 2 dims (one packed uint).
// 8-edge unroll: 8 independent gathers in flight per lane (MLP probe).
// ---------------------------------------------------------------------------
__global__ void agg_kernel(const unsigned* __restrict__ hb,
                           const int* __restrict__ offsets,
                           const int* __restrict__ csr,
                           unsigned* __restrict__ aggb, int n) {
    int node = blockIdx.x * 4 + (threadIdx.x >> 6);
    int lane = threadIdx.x & 63;
    if (node >= n) return;
    int e = offsets[node], end = offsets[node + 1];
    float lo4[4] = {0.f, 0.f, 0.f, 0.f}, hi4[4] = {0.f, 0.f, 0.f, 0.f};
    for (; e + 8 <= end; e += 8) {
        int idx[8];
        unsigned vv[8];
#pragma unroll
        for (int j = 0; j < 8; j++) idx[j] = csr[e + j];
#pragma unroll
        for (int j = 0; j < 8; j++) vv[j] = hb[idx[j] * 64 + lane];
#pragma unroll
        for (int j = 0; j < 8; j++) { lo4[j & 3] += blo(vv[j]); hi4[j & 3] += bhi(vv[j]); }
    }
    for (; e + 4 <= end; e += 4) {
        int idx[4];
        unsigned vv[4];
#pragma unroll
        for (int j = 0; j < 4; j++) idx[j] = csr[e + j];
#pragma unroll
        for (int j = 0; j < 4; j++) vv[j] = hb[idx[j] * 64 + lane];
#pragma unroll
        for (int j = 0; j < 4; j++) { lo4[j] += blo(vv[j]); hi4[j] += bhi(vv[j]); }
    }
    for (; e < end; ++e) {
        unsigned v = hb[csr[e] * 64 + lane];
        lo4[0] += blo(v); hi4[0] += bhi(v);
    }
    float s0 = (lo4[0] + lo4[1]) + (lo4[2] + lo4[3]);
    float s1 = (hi4[0] + hi4[1]) + (hi4[2] + hi4[3]);
    aggb[node * 64 + lane] = f2b(s0) | (f2b(s1) << 16);
}

// ---------------------------------------------------------------------------
// MFMA bf16 GEMM: out = A@Wr^T + H@Wt^T + bias (+relu for bf16 output).
// 128x128 tile per block, 4 waves; XOR-swizzled LDS.
// ---------------------------------------------------------------------------
template <int OUTF32>
__global__ __launch_bounds__(256, 2)
void mfma_gemm(const unsigned short* __restrict__ A,
               const unsigned short* __restrict__ H,
               const unsigned short* __restrict__ Wr,
               const unsigned short* __restrict__ Wt,
               const float* __restrict__ bias,
               void* __restrict__ outp, int n) {
    __shared__ __align__(16) char sIn[128 * 256];
    __shared__ __align__(16) char sW[128 * 256];
    int t = threadIdx.x;
    int l = t & 63, w = t >> 6;
    int row0 = blockIdx.x * 128;
    int lr = l & 15;
    int lk = (l >> 4) << 3;  // 0,8,16,24

    f32x4 acc[2][8];
#pragma unroll
    for (int i = 0; i < 2; i++)
#pragma unroll
        for (int j = 0; j < 8; j++) acc[i][j] = (f32x4){0.f, 0.f, 0.f, 0.f};

    for (int phase = 0; phase < 2; ++phase) {
        const unsigned short* In = phase ? H : A;
        const unsigned short* W = phase ? Wt : Wr;
        __syncthreads();  // previous phase done reading LDS
#pragma unroll
        for (int q = 0; q < 8; q++) {
            int idx = q * 256 + t;
            int r = idx >> 4, c = idx & 15;  // 128 rows x 16 chunks of 16B
            int gr = row0 + r; if (gr > n - 1) gr = n - 1;
            uint4 v = ((const uint4*)In)[(size_t)gr * 16 + c];
            *(uint4*)(sIn + r * 256 + ((c * 16) ^ ((r & 7) << 4))) = v;
            uint4 wv = ((const uint4*)W)[r * 16 + c];
            *(uint4*)(sW + r * 256 + ((c * 16) ^ ((r & 7) << 4))) = wv;
        }
        __syncthreads();
#pragma unroll
        for (int ks = 0; ks < 4; ++ks) {
            int kb = (ks * 32 + lk) * 2;  // byte offset of k within row
            short8 av[2], bv[8];
#pragma unroll
            for (int mt = 0; mt < 2; mt++) {
                int r = w * 32 + mt * 16 + lr;
                av[mt] = *(const short8*)(sIn + r * 256 + (kb ^ ((r & 7) << 4)));
            }
#pragma unroll
            for (int nt = 0; nt < 8; nt++) {
                int cw = nt * 16 + lr;
                bv[nt] = *(const short8*)(sW + cw * 256 + (kb ^ ((cw & 7) << 4)));
            }
#pragma unroll
            for (int mt = 0; mt < 2; mt++)
#pragma unroll
                for (int nt = 0; nt < 8; nt++)
                    acc[mt][nt] = __builtin_amdgcn_mfma_f32_16x16x32_bf16(
                        av[mt], bv[nt], acc[mt][nt], 0, 0, 0);
        }
    }

    // C/D layout (m89-verified): col = lane&15, row = (lane>>4)*4 + reg
    int rbase = row0 + w * 32 + ((l >> 4) << 2);
#pragma unroll
    for (int mt = 0; mt < 2; mt++) {
#pragma unroll
        for (int nt = 0; nt < 8; nt++) {
            int col = nt * 16 + lr;
            float bc = bias[col];
#pragma unroll
            for (int j = 0; j < 4; j++) {
                int row = rbase + mt * 16 + j;
                if (row < n) {
                    float v = acc[mt][nt][j] + bc;
                    if (OUTF32) {
                        ((float*)outp)[(size_t)row * DIM + col] = v;
                    } else {
                        v = fmaxf(v, 0.f);
                        ((unsigned short*)outp)[(size_t)row * DIM + col] =
                            (unsigned short)f2b(v);
                    }
                }
            }
        }
    }
}

// ---------------------------------------------------------------------------
extern "C" void kernel_launch(void* const* d_in, const int* in_sizes, int n_in,
                              void* d_out, int out_size, void* d_ws, size_t ws_size,
                              hipStream_t stream) {
    const int N = NN, E = NE;
    const float* x = (const float*)d_in[0];
    const void* ei = d_in[1];
    const float* W1r = (const float*)d_in[2];
    const float* W1t = (const float*)d_in[3];
    const float* b1 = (const float*)d_in[4];
    const float* W2r = (const float*)d_in[5];
    const float* W2t = (const float*)d_in[6];
    const float* b2 = (const float*)d_in[7];
    float* out = (float*)d_out;

    char* wsp = (char*)d_ws;
    auto alloc = [&](size_t bytes) {
        char* p = wsp;
        wsp += (bytes + 255) & ~(size_t)255;
        return p;
    };
    int* flag = (int*)alloc(4);
    int* deg = (int*)alloc((size_t)N * 4);
    int* claim = (int*)alloc((size_t)NCHUNK * 8 * 4);
    int* offsets = (int*)alloc((size_t)(N + 1) * 4);
    int* cursor = (int*)alloc((size_t)N * 4);
    int* bsum = (int*)alloc(512);
    int* csr_src = (int*)alloc((size_t)E * 4);
    unsigned short* w1rb = (unsigned short*)alloc(DIM * DIM * 2);
    unsigned short* w1tb = (unsigned short*)alloc(DIM * DIM * 2);
    unsigned short* w2rb = (unsigned short*)alloc(DIM * DIM * 2);
    unsigned short* w2tb = (unsigned short*)alloc(DIM * DIM * 2);
    unsigned short* xb = (unsigned short*)alloc((size_t)N * DIM * 2);   // becomes h (bf16)
    unsigned short* aggb = (unsigned short*)alloc((size_t)N * DIM * 2); // agg1 then agg2

    const int NB = (N + 1023) / 1024;  // 98

    hipMemsetAsync(deg, 0, (size_t)N * 4, stream);
    hipMemsetAsync(claim, 0, (size_t)NCHUNK * 8 * 4, stream);
    detect_kernel<<<1, 256, 0, stream>>>(ei, flag);

    // bf16 conversions (independent of CSR build)
    cvt_kernel<<<(N * DIM / 8 + 255) / 256, 256, 0, stream>>>(x, xb, N * DIM / 8);
    cvtw_kernel<<<32, 256, 0, stream>>>(W1r, W1t, W2r, W2t, w1rb, w1tb, w2rb, w2tb);

    // CSR by destination
    hist_kernel<<<(E + 1023) / 1024, 256, 0, stream>>>(ei, deg, flag, E);
    scan1<<<NB, 256, 0, stream>>>(deg, offsets, bsum, N);
    scan2<<<1, 128, 0, stream>>>(bsum, offsets, NB, N);
    scan3<<<NB, 256, 0, stream>>>(offsets, cursor, bsum, N);
    fill_kernel<<<NCHUNK * 8, 256, 0, stream>>>(ei, cursor, csr_src, flag, claim, E);

    // Layer 1: agg1 = segsum(xb); h = relu(agg1@W1r^T + x@W1t^T + b1) -> xb (bf16)
    agg_kernel<<<N / 4, 256, 0, stream>>>((const unsigned*)xb, offsets, csr_src,
                                          (unsigned*)aggb, N);
    mfma_gemm<0><<<(N + 127) / 128, 256, 0, stream>>>(aggb, xb, w1rb, w1tb, b1, xb, N);

    // Layer 2: agg2 = segsum(h); out = agg2@W2r^T + h@W2t^T + b2 (fp32)
    agg_kernel<<<N / 4, 256, 0, stream>>>((const unsigned*)xb, offsets, csr_src,
                                          (unsigned*)aggb, N);
    mfma_gemm<1><<<(N + 127) / 128, 256, 0, stream>>>(aggb, xb, w2rb, w2tb, b2, out, N);
}